// Round 1
// baseline (2316.430 us; speedup 1.0000x reference)
//
#include <hip/hip_runtime.h>

// Problem constants (fixed by the reference's setup_inputs).
#define DFEAT 64

__device__ __forceinline__ void atomic_add_f32(float* p, float v) {
#if defined(__gfx950__) || defined(__gfx942__) || defined(__gfx90a__)
    unsafeAtomicAdd(p, v);   // hardware global_atomic_add_f32 (no CAS loop)
#else
    atomicAdd(p, v);
#endif
}

// Edge aggregation: 16 threads per edge, one float4 per thread (256 B row).
// Lanes 0-15 of each 16-thread group read a contiguous 256 B segment -> good
// coalescing (4 segments per wave64). Scatter via hw fp32 atomics.
__global__ __launch_bounds__(256) void edge_agg(const float* __restrict__ feat,
                                                const int* __restrict__ src,
                                                const int* __restrict__ dst,
                                                float* __restrict__ agg,
                                                float* __restrict__ deg,
                                                int n_edges,
                                                int count_deg) {
    int t = blockIdx.x * 256 + threadIdx.x;
    int e = t >> 4;
    int c = t & 15;
    if (e >= n_edges) return;
    int s = src[e];
    int d = dst[e];
    float4 v = ((const float4*)(feat + (size_t)s * DFEAT))[c];
    float* arow = agg + (size_t)d * DFEAT + c * 4;
    atomic_add_f32(arow + 0, v.x);
    atomic_add_f32(arow + 1, v.y);
    atomic_add_f32(arow + 2, v.z);
    atomic_add_f32(arow + 3, v.w);
    if (count_deg && c == 0) atomic_add_f32(deg + d, 1.0f);
}

// Node update: out[v] = (feat[v] @ Wself) + b + (agg[v]/max(deg,1)) @ Wneigh,
// optional ReLU. One wave per node, lane = output column. W staged in LDS
// (row broadcast via shuffle; LDS reads are stride-1 -> free 2-way aliasing).
__global__ __launch_bounds__(256) void sage_node(const float* __restrict__ feat,
                                                 const float* __restrict__ agg,
                                                 const float* __restrict__ deg,
                                                 const float* __restrict__ Wself,
                                                 const float* __restrict__ Wneigh,
                                                 const float* __restrict__ bias,
                                                 float* __restrict__ out,
                                                 int n_nodes,
                                                 int do_relu) {
    __shared__ float ws[DFEAT * DFEAT];
    __shared__ float wn[DFEAT * DFEAT];
    for (int i = threadIdx.x; i < DFEAT * DFEAT / 4; i += 256) {
        ((float4*)ws)[i] = ((const float4*)Wself)[i];
        ((float4*)wn)[i] = ((const float4*)Wneigh)[i];
    }
    __syncthreads();

    const int lane = threadIdx.x & 63;
    const int wave = threadIdx.x >> 6;
    const float bl = bias[lane];

    for (int v = blockIdx.x * 4 + wave; v < n_nodes; v += gridDim.x * 4) {
        float xv = feat[(size_t)v * DFEAT + lane];
        float dg = deg[v];
        float inv = 1.0f / fmaxf(dg, 1.0f);
        float mv = agg[(size_t)v * DFEAT + lane] * inv;
        float acc = bl;
#pragma unroll
        for (int k = 0; k < DFEAT; ++k) {
            float xk = __shfl(xv, k, 64);
            float mk = __shfl(mv, k, 64);
            acc += xk * ws[k * DFEAT + lane];
            acc += mk * wn[k * DFEAT + lane];
        }
        if (do_relu) acc = fmaxf(acc, 0.0f);
        out[(size_t)v * DFEAT + lane] = acc;
    }
}

extern "C" void kernel_launch(void* const* d_in, const int* in_sizes, int n_in,
                              void* d_out, int out_size, void* d_ws, size_t ws_size,
                              hipStream_t stream) {
    const float* x       = (const float*)d_in[0];
    const int*   src     = (const int*)d_in[1];
    const int*   dst     = (const int*)d_in[2];
    const float* Wself1  = (const float*)d_in[3];
    const float* Wneigh1 = (const float*)d_in[4];
    const float* b1      = (const float*)d_in[5];
    const float* Wself2  = (const float*)d_in[6];
    const float* Wneigh2 = (const float*)d_in[7];
    const float* b2      = (const float*)d_in[8];
    float* out = (float*)d_out;

    const int n_nodes = in_sizes[0] / DFEAT;
    const int n_edges = in_sizes[1];

    // Workspace layout: agg [N*D] | h [N*D] | deg [N]
    float* agg = (float*)d_ws;
    float* h   = agg + (size_t)n_nodes * DFEAT;
    float* deg = h + (size_t)n_nodes * DFEAT;

    const size_t agg_bytes = (size_t)n_nodes * DFEAT * sizeof(float);
    const size_t deg_bytes = (size_t)n_nodes * sizeof(float);

    const int edge_blocks = (n_edges * 16 + 255) / 256;
    const int node_blocks = (n_nodes + 3) / 4;

    // ---- Layer 1 ----
    hipMemsetAsync(agg, 0, agg_bytes, stream);
    hipMemsetAsync(deg, 0, deg_bytes, stream);
    edge_agg<<<edge_blocks, 256, 0, stream>>>(x, src, dst, agg, deg, n_edges, 1);
    sage_node<<<node_blocks, 256, 0, stream>>>(x, agg, deg, Wself1, Wneigh1, b1,
                                               h, n_nodes, 1);

    // ---- Layer 2 ----
    hipMemsetAsync(agg, 0, agg_bytes, stream);
    edge_agg<<<edge_blocks, 256, 0, stream>>>(h, src, dst, agg, deg, n_edges, 0);
    sage_node<<<node_blocks, 256, 0, stream>>>(h, agg, deg, Wself2, Wneigh2, b2,
                                               out, n_nodes, 0);
}

// Round 2
// 471.835 us; speedup vs baseline: 4.9094x; 4.9094x over previous
//
#include <hip/hip_runtime.h>

#define DFEAT 64

// ---------------- CSR build: histogram -> scan -> scatter ----------------

__global__ __launch_bounds__(256) void hist_kernel(const int* __restrict__ dst,
                                                   int* __restrict__ cnt,
                                                   int n_edges) {
    int e = blockIdx.x * 256 + threadIdx.x;
    if (e < n_edges) atomicAdd(&cnt[dst[e]], 1);
}

// Block-level exclusive scan, 1024 elements per block (256 thr x 4).
__global__ __launch_bounds__(256) void scan1(const int* __restrict__ cnt,
                                             int* __restrict__ start,
                                             int* __restrict__ bsum, int n) {
    __shared__ int sh[256];
    int base = blockIdx.x * 1024;
    int i0 = base + threadIdx.x * 4;
    int vals[4];
    int tsum = 0;
#pragma unroll
    for (int j = 0; j < 4; ++j) {
        int idx = i0 + j;
        int v = (idx < n) ? cnt[idx] : 0;
        vals[j] = v;
        tsum += v;
    }
    sh[threadIdx.x] = tsum;
    __syncthreads();
    for (int off = 1; off < 256; off <<= 1) {
        int v = (threadIdx.x >= off) ? sh[threadIdx.x - off] : 0;
        __syncthreads();
        sh[threadIdx.x] += v;
        __syncthreads();
    }
    int excl = sh[threadIdx.x] - tsum;
    if (threadIdx.x == 255) bsum[blockIdx.x] = sh[255];
#pragma unroll
    for (int j = 0; j < 4; ++j) {
        int idx = i0 + j;
        if (idx < n) start[idx] = excl;
        excl += vals[j];
    }
}

// Scan the (<=256) block sums in one block.
__global__ __launch_bounds__(256) void scan2(int* __restrict__ bsum, int nb) {
    __shared__ int sh[256];
    int t = threadIdx.x;
    int v = (t < nb) ? bsum[t] : 0;
    sh[t] = v;
    __syncthreads();
    for (int off = 1; off < 256; off <<= 1) {
        int u = (t >= off) ? sh[t - off] : 0;
        __syncthreads();
        sh[t] += u;
        __syncthreads();
    }
    if (t < nb) bsum[t] = sh[t] - v;  // exclusive
}

// Add block offsets; also init the scatter cursor.
__global__ __launch_bounds__(256) void scan3(int* __restrict__ start,
                                             const int* __restrict__ bsum,
                                             int* __restrict__ cursor, int n) {
    int idx = blockIdx.x * 256 + threadIdx.x;
    if (idx < n) {
        int s = start[idx] + bsum[idx >> 10];
        start[idx] = s;
        cursor[idx] = s;
    }
}

__global__ __launch_bounds__(256) void scatter_kernel(const int* __restrict__ src,
                                                      const int* __restrict__ dst,
                                                      int* __restrict__ cursor,
                                                      int* __restrict__ sorted_src,
                                                      int n_edges) {
    int e = blockIdx.x * 256 + threadIdx.x;
    if (e < n_edges) {
        int p = atomicAdd(&cursor[dst[e]], 1);
        sorted_src[p] = src[e];
    }
}

// ---------------- Pull-mode mean aggregation (no atomics) ----------------
// One wave per node, lane = feature column. Neighbor indices loaded 64 at a
// time coalesced, broadcast to the wave via shuffle; each row gather is one
// contiguous 256 B transaction.
__global__ __launch_bounds__(256) void aggregate(const float* __restrict__ feat,
                                                 const int* __restrict__ sorted_src,
                                                 const int* __restrict__ start,
                                                 const int* __restrict__ cnt,
                                                 float* __restrict__ mean_out,
                                                 int n_nodes) {
    const int lane = threadIdx.x & 63;
    const int wave = threadIdx.x >> 6;
    int v = blockIdx.x * 4 + wave;
    if (v >= n_nodes) return;
    int s0 = start[v];
    int c = cnt[v];
    float sum = 0.0f;
    for (int base = 0; base < c; base += 64) {
        int m = min(64, c - base);
        int idx = (lane < m) ? sorted_src[s0 + base + lane] : 0;
        for (int i = 0; i < m; ++i) {
            int s = __shfl(idx, i, 64);
            sum += feat[(size_t)s * DFEAT + lane];
        }
    }
    float inv = (c > 0) ? 1.0f / (float)c : 0.0f;
    mean_out[(size_t)v * DFEAT + lane] = sum * inv;
}

// ---------------- Node GEMM: thread per node, W via SGPRs ----------------
// acc[64] lives in VGPRs; W[k][j] and bias[j] are wave-uniform loads the
// compiler scalarizes (s_load), so each FMA is v_fmac(acc, sW, v_xk) with no
// LDS traffic and no shuffles.
__global__ __launch_bounds__(256) void gemm_node(const float* __restrict__ x,
                                                 const float* __restrict__ mean,
                                                 const float* __restrict__ Wself,
                                                 const float* __restrict__ Wneigh,
                                                 const float* __restrict__ bias,
                                                 float* __restrict__ out,
                                                 int n_nodes, int do_relu) {
    int v = blockIdx.x * 256 + threadIdx.x;
    if (v >= n_nodes) return;

    float acc[DFEAT];
#pragma unroll
    for (int j = 0; j < DFEAT; ++j) acc[j] = bias[j];

    const float4* xr = (const float4*)(x + (size_t)v * DFEAT);
#pragma unroll 4
    for (int kc = 0; kc < DFEAT / 4; ++kc) {
        float4 xv = xr[kc];
        const float* w0 = Wself + (kc * 4 + 0) * DFEAT;
        const float* w1 = Wself + (kc * 4 + 1) * DFEAT;
        const float* w2 = Wself + (kc * 4 + 2) * DFEAT;
        const float* w3 = Wself + (kc * 4 + 3) * DFEAT;
#pragma unroll
        for (int j = 0; j < DFEAT; ++j)
            acc[j] += xv.x * w0[j] + xv.y * w1[j] + xv.z * w2[j] + xv.w * w3[j];
    }

    const float4* mr = (const float4*)(mean + (size_t)v * DFEAT);
#pragma unroll 4
    for (int kc = 0; kc < DFEAT / 4; ++kc) {
        float4 mv = mr[kc];
        const float* w0 = Wneigh + (kc * 4 + 0) * DFEAT;
        const float* w1 = Wneigh + (kc * 4 + 1) * DFEAT;
        const float* w2 = Wneigh + (kc * 4 + 2) * DFEAT;
        const float* w3 = Wneigh + (kc * 4 + 3) * DFEAT;
#pragma unroll
        for (int j = 0; j < DFEAT; ++j)
            acc[j] += mv.x * w0[j] + mv.y * w1[j] + mv.z * w2[j] + mv.w * w3[j];
    }

    float4* orow = (float4*)(out + (size_t)v * DFEAT);
#pragma unroll
    for (int jc = 0; jc < DFEAT / 4; ++jc) {
        float4 r;
        r.x = acc[jc * 4 + 0];
        r.y = acc[jc * 4 + 1];
        r.z = acc[jc * 4 + 2];
        r.w = acc[jc * 4 + 3];
        if (do_relu) {
            r.x = fmaxf(r.x, 0.0f);
            r.y = fmaxf(r.y, 0.0f);
            r.z = fmaxf(r.z, 0.0f);
            r.w = fmaxf(r.w, 0.0f);
        }
        orow[jc] = r;
    }
}

// -------------------------------------------------------------------------

extern "C" void kernel_launch(void* const* d_in, const int* in_sizes, int n_in,
                              void* d_out, int out_size, void* d_ws, size_t ws_size,
                              hipStream_t stream) {
    const float* x       = (const float*)d_in[0];
    const int*   src     = (const int*)d_in[1];
    const int*   dst     = (const int*)d_in[2];
    const float* Wself1  = (const float*)d_in[3];
    const float* Wneigh1 = (const float*)d_in[4];
    const float* b1      = (const float*)d_in[5];
    const float* Wself2  = (const float*)d_in[6];
    const float* Wneigh2 = (const float*)d_in[7];
    const float* b2      = (const float*)d_in[8];
    float* out = (float*)d_out;

    const int n_nodes = in_sizes[0] / DFEAT;
    const int n_edges = in_sizes[1];

    // Workspace layout (ints then floats):
    // cnt[N] | start[N] | cursor[N] | bsum[256] | sorted_src[E] | mean[N*D]
    int* cnt        = (int*)d_ws;
    int* start      = cnt + n_nodes;
    int* cursor     = start + n_nodes;
    int* bsum       = cursor + n_nodes;
    int* sorted_src = bsum + 256;
    float* mean     = (float*)(sorted_src + n_edges);
    float* h        = out;  // layer-1 activations live in d_out (safe: each
                            // gemm thread reads only its own row before writing)

    const int eb  = (n_edges + 255) / 256;        // edge-parallel blocks
    const int nb  = (n_nodes + 255) / 256;        // node-parallel blocks
    const int wb  = (n_nodes + 3) / 4;            // wave-per-node blocks
    const int sb  = (n_nodes + 1023) / 1024;      // scan1 blocks (<=256)

    // ---- CSR build (shared by both layers) ----
    hipMemsetAsync(cnt, 0, (size_t)n_nodes * sizeof(int), stream);
    hist_kernel<<<eb, 256, 0, stream>>>(dst, cnt, n_edges);
    scan1<<<sb, 256, 0, stream>>>(cnt, start, bsum, n_nodes);
    scan2<<<1, 256, 0, stream>>>(bsum, sb);
    scan3<<<nb, 256, 0, stream>>>(start, bsum, cursor, n_nodes);
    scatter_kernel<<<eb, 256, 0, stream>>>(src, dst, cursor, sorted_src, n_edges);

    // ---- Layer 1 ----
    aggregate<<<wb, 256, 0, stream>>>(x, sorted_src, start, cnt, mean, n_nodes);
    gemm_node<<<nb, 256, 0, stream>>>(x, mean, Wself1, Wneigh1, b1, h, n_nodes, 1);

    // ---- Layer 2 ----
    aggregate<<<wb, 256, 0, stream>>>(h, sorted_src, start, cnt, mean, n_nodes);
    gemm_node<<<nb, 256, 0, stream>>>(h, mean, Wself2, Wneigh2, b2, out, n_nodes, 0);
}